// Round 6
// baseline (217.483 us; speedup 1.0000x reference)
//
#include <hip/hip_runtime.h>

// MonarchLinear: x[16384,256] fp32, L[68,68,68], R[68,68,68], bias[4608] -> out[16384,4608] fp32.
//   t1[b,r,l] = sum_p x[b, r*68+p] * L[r,l,p]           (r<4; r==3 only p<52 valid)
//   out[b, s*68+l] = sum_{r<4} t1[b,r,l] * R[l,s,r] + bias[s*68+l]
//
// Round 6 DIAGNOSTIC: stage2 writes output TWICE — to d_out and to a mirror in
// d_ws. All prior variants (134-153us) write d_out at ~2.5 TB/s effective while
// the harness fill writes d_ws (1.2GB) at 6.9 TB/s with plain stores. This A/B
// separates "d_out buffer is slow" from "our store stream is slow":
//   ~185us -> ws mirror absorbed at ~7TB/s, d_out is the wall (buffer identity)
//   ~250us -> both streams ~2.5 TB/s, kernel-side store-path problem
//   ~145us -> extra writes free, we were never drain-limited
// Also pushes the stage2 dispatch into rocprof top-5 on BOTH passes (counters!).

typedef float f4 __attribute__((ext_vector_type(4)));

namespace {
constexpr int MM     = 68;
constexpr int IN_D   = 256;
constexpr int OUT_D  = 4608;
constexpr int T_TILE = 16;
constexpr int NTH    = 256;
constexpr int NJ     = 5;
constexpr int T1W    = 4 * MM;    // 272 floats per token in t1
}

// ---------------- stage 1: t1[b][r*68+l] ----------------
__global__ __launch_bounds__(NTH, 6)
void monarch_stage1(const float* __restrict__ x, const float* __restrict__ L,
                    float* __restrict__ t1ws)
{
  __shared__ float t1s[T_TILE * T1W];
  const int tid = threadIdx.x;
  const long tb = (long)blockIdx.x * T_TILE;

  for (int idx = tid; idx < T1W; idx += NTH) {
    const int r = idx / MM;
    const float* Lp = L + (size_t)idx * MM;
    const float* xp = x + tb * IN_D + r * MM;
    const int p4max = (r == 3) ? (IN_D - 3 * MM) / 4 : MM / 4;   // 13 or 17
    float acc[T_TILE];
#pragma unroll
    for (int t = 0; t < T_TILE; ++t) acc[t] = 0.f;
    for (int p4 = 0; p4 < p4max; ++p4) {
      f4 Lv = *(const f4*)(Lp + p4 * 4);
#pragma unroll
      for (int t = 0; t < T_TILE; ++t) {
        f4 xv = *(const f4*)(xp + (size_t)t * IN_D + p4 * 4);
        acc[t] = fmaf(Lv.x, xv.x, acc[t]);
        acc[t] = fmaf(Lv.y, xv.y, acc[t]);
        acc[t] = fmaf(Lv.z, xv.z, acc[t]);
        acc[t] = fmaf(Lv.w, xv.w, acc[t]);
      }
    }
#pragma unroll
    for (int t = 0; t < T_TILE; ++t) t1s[t * T1W + idx] = acc[t];
  }
  __syncthreads();
  float* wp = t1ws + tb * T1W;
#pragma unroll
  for (int k = 0; k < (T_TILE * T1W) / NTH; ++k)
    wp[tid + k * NTH] = t1s[tid + k * NTH];
}

// ---------------- stage 2 (templated on dual-write) ----------------
template <bool DUAL>
__global__ __launch_bounds__(NTH, 3)
void monarch_stage2(const float* __restrict__ t1ws, const float* __restrict__ R,
                    const float* __restrict__ bias, float* __restrict__ out,
                    float* __restrict__ out2)
{
  __shared__ float t1s[T_TILE * T1W];
  const int tid = threadIdx.x;
  const long tb = (long)blockIdx.x * T_TILE;

  const int g  = tid / 17;
  const int m  = tid - g * 17;
  const int l4 = 4 * m;

  f4 Rr[NJ][4];
  f4 br[NJ];
  int scol[NJ];
  bool act[NJ];
#pragma unroll
  for (int j = 0; j < NJ; ++j) {
    int s = g + 15 * j;
    act[j]  = (tid < 255) && (s < MM) && (s < MM - 1 || m < 13);  // 4608 = 67*68+52
    scol[j] = s * MM + l4;
    if (act[j]) {
      br[j] = *(const f4*)(bias + scol[j]);
#pragma unroll
      for (int q = 0; q < 4; ++q)
        Rr[j][q] = *(const f4*)(R + (size_t)(l4 + q) * (MM * MM) + (size_t)s * MM);
    }
  }

  const float* rp = t1ws + tb * T1W;
#pragma unroll
  for (int k = 0; k < (T_TILE * T1W) / NTH; ++k)
    t1s[tid + k * NTH] = rp[tid + k * NTH];
  __syncthreads();

#pragma unroll 2
  for (int t = 0; t < T_TILE; ++t) {
    const float* t1p = t1s + t * T1W + l4;
    f4 a0 = *(const f4*)(t1p);
    f4 a1 = *(const f4*)(t1p + MM);
    f4 a2 = *(const f4*)(t1p + 2 * MM);
    f4 a3 = *(const f4*)(t1p + 3 * MM);
    float* op  = out  + (tb + t) * OUT_D;
    float* op2 = DUAL ? out2 + (tb + t) * OUT_D : nullptr;
#pragma unroll
    for (int j = 0; j < NJ; ++j) {
      if (act[j]) {
        f4 o;
#pragma unroll
        for (int q = 0; q < 4; ++q) {
          float oq = br[j][q];
          oq = fmaf(a0[q], Rr[j][q].x, oq);
          oq = fmaf(a1[q], Rr[j][q].y, oq);
          oq = fmaf(a2[q], Rr[j][q].z, oq);
          oq = fmaf(a3[q], Rr[j][q].w, oq);
          o[q] = oq;
        }
        *(f4*)(op + scol[j]) = o;
        if (DUAL) *(f4*)(op2 + scol[j]) = o;     // mirror stream into d_ws
      }
    }
  }
}

// ---------------- fused fallback ----------------
__global__ __launch_bounds__(NTH, 2)
void monarch_fused(const float* __restrict__ x, const float* __restrict__ L,
                   const float* __restrict__ R, const float* __restrict__ bias,
                   float* __restrict__ out)
{
  __shared__ float t1s[T_TILE * T1W];
  const int tid = threadIdx.x;
  const long tb = (long)blockIdx.x * T_TILE;
  const int g  = tid / 17;
  const int m  = tid - g * 17;
  const int l4 = 4 * m;
  f4 Rr[NJ][4]; f4 br[NJ]; int scol[NJ]; bool act[NJ];
#pragma unroll
  for (int j = 0; j < NJ; ++j) {
    int s = g + 15 * j;
    act[j]  = (tid < 255) && (s < MM) && (s < MM - 1 || m < 13);
    scol[j] = s * MM + l4;
    if (act[j]) {
      br[j] = *(const f4*)(bias + scol[j]);
#pragma unroll
      for (int q = 0; q < 4; ++q)
        Rr[j][q] = *(const f4*)(R + (size_t)(l4 + q) * (MM * MM) + (size_t)s * MM);
    }
  }
  for (int idx = tid; idx < T1W; idx += NTH) {
    const int r = idx / MM;
    const float* Lp = L + (size_t)idx * MM;
    const float* xp = x + tb * IN_D + r * MM;
    const int p4max = (r == 3) ? (IN_D - 3 * MM) / 4 : MM / 4;
    float acc[T_TILE];
#pragma unroll
    for (int t = 0; t < T_TILE; ++t) acc[t] = 0.f;
    for (int p4 = 0; p4 < p4max; ++p4) {
      f4 Lv = *(const f4*)(Lp + p4 * 4);
#pragma unroll
      for (int t = 0; t < T_TILE; ++t) {
        f4 xv = *(const f4*)(xp + (size_t)t * IN_D + p4 * 4);
        acc[t] = fmaf(Lv.x, xv.x, acc[t]);
        acc[t] = fmaf(Lv.y, xv.y, acc[t]);
        acc[t] = fmaf(Lv.z, xv.z, acc[t]);
        acc[t] = fmaf(Lv.w, xv.w, acc[t]);
      }
    }
#pragma unroll
    for (int t = 0; t < T_TILE; ++t) t1s[t * T1W + idx] = acc[t];
  }
  __syncthreads();
#pragma unroll 2
  for (int t = 0; t < T_TILE; ++t) {
    const float* t1p = t1s + t * T1W + l4;
    f4 a0 = *(const f4*)(t1p);
    f4 a1 = *(const f4*)(t1p + MM);
    f4 a2 = *(const f4*)(t1p + 2 * MM);
    f4 a3 = *(const f4*)(t1p + 3 * MM);
    float* op = out + (tb + t) * OUT_D;
#pragma unroll
    for (int j = 0; j < NJ; ++j) {
      if (act[j]) {
        f4 o;
#pragma unroll
        for (int q = 0; q < 4; ++q) {
          float oq = br[j][q];
          oq = fmaf(a0[q], Rr[j][q].x, oq);
          oq = fmaf(a1[q], Rr[j][q].y, oq);
          oq = fmaf(a2[q], Rr[j][q].z, oq);
          oq = fmaf(a3[q], Rr[j][q].w, oq);
          o[q] = oq;
        }
        *(f4*)(op + scol[j]) = o;
      }
    }
  }
}

extern "C" void kernel_launch(void* const* d_in, const int* in_sizes, int n_in,
                              void* d_out, int out_size, void* d_ws, size_t ws_size,
                              hipStream_t stream) {
  const float* x    = (const float*)d_in[0];
  const float* L    = (const float*)d_in[1];
  const float* R    = (const float*)d_in[2];
  const float* bias = (const float*)d_in[3];
  float* out = (float*)d_out;

  const int ntok    = in_sizes[0] / IN_D;                    // 16384
  const int nblk    = ntok / T_TILE;                         // 1024
  const size_t t1b  = (size_t)ntok * T1W * sizeof(float);    // 17.8 MB
  const size_t outb = (size_t)out_size * sizeof(float);      // 302 MB

  if (ws_size >= t1b + outb) {
    float* t1ws = (float*)d_ws;
    float* mirror = (float*)((char*)d_ws + t1b);             // t1b is 256B-aligned
    monarch_stage1<<<nblk, NTH, 0, stream>>>(x, L, t1ws);
    monarch_stage2<true><<<nblk, NTH, 0, stream>>>(t1ws, R, bias, out, mirror);
  } else if (ws_size >= t1b) {
    float* t1ws = (float*)d_ws;
    monarch_stage1<<<nblk, NTH, 0, stream>>>(x, L, t1ws);
    monarch_stage2<false><<<nblk, NTH, 0, stream>>>(t1ws, R, bias, out, nullptr);
  } else {
    monarch_fused<<<nblk, NTH, 0, stream>>>(x, L, R, bias, out);
  }
}

// Round 7
// 130.128 us; speedup vs baseline: 1.6713x; 1.6713x over previous
//
#include <hip/hip_runtime.h>

// MonarchLinear: x[16384,256] fp32, L[68,68,68], R[68,68,68], bias[4608] -> out[16384,4608] fp32.
//   t1[b,r,l] = sum_p x[b, r*68+p] * L[r,l,p]           (r<4; r==3 only p<52 valid)
//   out[b, s*68+l] = sum_{r<4} t1[b,r,l] * R[l,s,r] + bias[s*68+l]
//
// Round 7: stage2 loop inversion. Round-3 profile showed VGPR_Count=80 while the
// hoisted Rr/br state needs >100 regs -> compiler SANK the R loads into the token
// loop. Each R load is a 64-line scatter (~64 TA cycles/wave): 16 waves x 320
// sunk loads x ~64cy ~= 136us/CU — the observed plateau. Fix: j OUTER (rolled),
// t INNER; per j only 20 hoisted regs (R0..R3+bias), scatter loads 320 -> 25/wave.

typedef float f4 __attribute__((ext_vector_type(4)));

namespace {
constexpr int MM     = 68;
constexpr int IN_D   = 256;
constexpr int OUT_D  = 4608;
constexpr int T_TILE = 16;
constexpr int NTH    = 256;
constexpr int NJ     = 5;
constexpr int T1W    = 4 * MM;    // 272 floats per token in t1
}

// ---------------- stage 1: t1[b][r*68+l] ----------------
__global__ __launch_bounds__(NTH, 6)
void monarch_stage1(const float* __restrict__ x, const float* __restrict__ L,
                    float* __restrict__ t1ws)
{
  __shared__ float t1s[T_TILE * T1W];
  const int tid = threadIdx.x;
  const long tb = (long)blockIdx.x * T_TILE;

  for (int idx = tid; idx < T1W; idx += NTH) {
    const int r = idx / MM;
    const float* Lp = L + (size_t)idx * MM;
    const float* xp = x + tb * IN_D + r * MM;
    const int p4max = (r == 3) ? (IN_D - 3 * MM) / 4 : MM / 4;   // 13 or 17
    float acc[T_TILE];
#pragma unroll
    for (int t = 0; t < T_TILE; ++t) acc[t] = 0.f;
    for (int p4 = 0; p4 < p4max; ++p4) {
      f4 Lv = *(const f4*)(Lp + p4 * 4);
#pragma unroll
      for (int t = 0; t < T_TILE; ++t) {
        f4 xv = *(const f4*)(xp + (size_t)t * IN_D + p4 * 4);
        acc[t] = fmaf(Lv.x, xv.x, acc[t]);
        acc[t] = fmaf(Lv.y, xv.y, acc[t]);
        acc[t] = fmaf(Lv.z, xv.z, acc[t]);
        acc[t] = fmaf(Lv.w, xv.w, acc[t]);
      }
    }
#pragma unroll
    for (int t = 0; t < T_TILE; ++t) t1s[t * T1W + idx] = acc[t];
  }
  __syncthreads();
  float* wp = t1ws + tb * T1W;
#pragma unroll
  for (int k = 0; k < (T_TILE * T1W) / NTH; ++k)
    wp[tid + k * NTH] = t1s[tid + k * NTH];
}

// ---------------- stage 2: j outer (rolled), t inner ----------------
__global__ __launch_bounds__(NTH, 4)
void monarch_stage2(const float* __restrict__ t1ws, const float* __restrict__ R,
                    const float* __restrict__ bias, float* __restrict__ out)
{
  __shared__ float t1s[T_TILE * T1W];
  const int tid = threadIdx.x;
  const long tb = (long)blockIdx.x * T_TILE;

  const int g  = tid / 17;
  const int m  = tid - g * 17;
  const int l4 = 4 * m;

  // stage t1 tile (4352 floats, 17 contiguous sweeps)
  const float* rp = t1ws + tb * T1W;
#pragma unroll
  for (int k = 0; k < (T_TILE * T1W) / NTH; ++k)
    t1s[tid + k * NTH] = rp[tid + k * NTH];
  __syncthreads();

#pragma unroll 1                       // keep j ROLLED: 20 hoisted regs per iter
  for (int j = 0; j < NJ; ++j) {
    const int s = g + 15 * j;
    // tid==255 (g==15,m==0) duplicates (g=0,j+1); s==67 row has only 52 cols (m<13)
    const bool act = (tid < 255) && (s < MM) && (s < MM - 1 || m < 13);
    const int scol = s * MM + l4;
    f4 R0, R1, R2, R3, bv;
    if (act) {
      R0 = *(const f4*)(R + (size_t)(l4 + 0) * (MM * MM) + (size_t)s * MM);
      R1 = *(const f4*)(R + (size_t)(l4 + 1) * (MM * MM) + (size_t)s * MM);
      R2 = *(const f4*)(R + (size_t)(l4 + 2) * (MM * MM) + (size_t)s * MM);
      R3 = *(const f4*)(R + (size_t)(l4 + 3) * (MM * MM) + (size_t)s * MM);
      bv = *(const f4*)(bias + scol);
    }
#pragma unroll 2
    for (int t = 0; t < T_TILE; ++t) {
      if (act) {
        const float* t1p = t1s + t * T1W + l4;
        f4 a0 = *(const f4*)(t1p);
        f4 a1 = *(const f4*)(t1p + MM);
        f4 a2 = *(const f4*)(t1p + 2 * MM);
        f4 a3 = *(const f4*)(t1p + 3 * MM);
        f4 o;
        o.x = fmaf(a3.x, R0.w, fmaf(a2.x, R0.z, fmaf(a1.x, R0.y, fmaf(a0.x, R0.x, bv.x))));
        o.y = fmaf(a3.y, R1.w, fmaf(a2.y, R1.z, fmaf(a1.y, R1.y, fmaf(a0.y, R1.x, bv.y))));
        o.z = fmaf(a3.z, R2.w, fmaf(a2.z, R2.z, fmaf(a1.z, R2.y, fmaf(a0.z, R2.x, bv.z))));
        o.w = fmaf(a3.w, R3.w, fmaf(a2.w, R3.z, fmaf(a1.w, R3.y, fmaf(a0.w, R3.x, bv.w))));
        *(f4*)(out + (tb + t) * OUT_D + scol) = o;
      }
    }
  }
}

// ---------------- fused fallback (ws too small; same j-outer structure) ----------------
__global__ __launch_bounds__(NTH, 2)
void monarch_fused(const float* __restrict__ x, const float* __restrict__ L,
                   const float* __restrict__ R, const float* __restrict__ bias,
                   float* __restrict__ out)
{
  __shared__ float t1s[T_TILE * T1W];
  const int tid = threadIdx.x;
  const long tb = (long)blockIdx.x * T_TILE;
  const int g  = tid / 17;
  const int m  = tid - g * 17;
  const int l4 = 4 * m;

  for (int idx = tid; idx < T1W; idx += NTH) {
    const int r = idx / MM;
    const float* Lp = L + (size_t)idx * MM;
    const float* xp = x + tb * IN_D + r * MM;
    const int p4max = (r == 3) ? (IN_D - 3 * MM) / 4 : MM / 4;
    float acc[T_TILE];
#pragma unroll
    for (int t = 0; t < T_TILE; ++t) acc[t] = 0.f;
    for (int p4 = 0; p4 < p4max; ++p4) {
      f4 Lv = *(const f4*)(Lp + p4 * 4);
#pragma unroll
      for (int t = 0; t < T_TILE; ++t) {
        f4 xv = *(const f4*)(xp + (size_t)t * IN_D + p4 * 4);
        acc[t] = fmaf(Lv.x, xv.x, acc[t]);
        acc[t] = fmaf(Lv.y, xv.y, acc[t]);
        acc[t] = fmaf(Lv.z, xv.z, acc[t]);
        acc[t] = fmaf(Lv.w, xv.w, acc[t]);
      }
    }
#pragma unroll
    for (int t = 0; t < T_TILE; ++t) t1s[t * T1W + idx] = acc[t];
  }
  __syncthreads();

#pragma unroll 1
  for (int j = 0; j < NJ; ++j) {
    const int s = g + 15 * j;
    const bool act = (tid < 255) && (s < MM) && (s < MM - 1 || m < 13);
    const int scol = s * MM + l4;
    f4 R0, R1, R2, R3, bv;
    if (act) {
      R0 = *(const f4*)(R + (size_t)(l4 + 0) * (MM * MM) + (size_t)s * MM);
      R1 = *(const f4*)(R + (size_t)(l4 + 1) * (MM * MM) + (size_t)s * MM);
      R2 = *(const f4*)(R + (size_t)(l4 + 2) * (MM * MM) + (size_t)s * MM);
      R3 = *(const f4*)(R + (size_t)(l4 + 3) * (MM * MM) + (size_t)s * MM);
      bv = *(const f4*)(bias + scol);
    }
#pragma unroll 2
    for (int t = 0; t < T_TILE; ++t) {
      if (act) {
        const float* t1p = t1s + t * T1W + l4;
        f4 a0 = *(const f4*)(t1p);
        f4 a1 = *(const f4*)(t1p + MM);
        f4 a2 = *(const f4*)(t1p + 2 * MM);
        f4 a3 = *(const f4*)(t1p + 3 * MM);
        f4 o;
        o.x = fmaf(a3.x, R0.w, fmaf(a2.x, R0.z, fmaf(a1.x, R0.y, fmaf(a0.x, R0.x, bv.x))));
        o.y = fmaf(a3.y, R1.w, fmaf(a2.y, R1.z, fmaf(a1.y, R1.y, fmaf(a0.y, R1.x, bv.y))));
        o.z = fmaf(a3.z, R2.w, fmaf(a2.z, R2.z, fmaf(a1.z, R2.y, fmaf(a0.z, R2.x, bv.z))));
        o.w = fmaf(a3.w, R3.w, fmaf(a2.w, R3.z, fmaf(a1.w, R3.y, fmaf(a0.w, R3.x, bv.w))));
        *(f4*)(out + (tb + t) * OUT_D + scol) = o;
      }
    }
  }
}

extern "C" void kernel_launch(void* const* d_in, const int* in_sizes, int n_in,
                              void* d_out, int out_size, void* d_ws, size_t ws_size,
                              hipStream_t stream) {
  const float* x    = (const float*)d_in[0];
  const float* L    = (const float*)d_in[1];
  const float* R    = (const float*)d_in[2];
  const float* bias = (const float*)d_in[3];
  float* out = (float*)d_out;

  const int ntok   = in_sizes[0] / IN_D;                    // 16384
  const int nblk   = ntok / T_TILE;                         // 1024
  const size_t t1b = (size_t)ntok * T1W * sizeof(float);    // 17.8 MB

  if (ws_size >= t1b) {
    float* t1ws = (float*)d_ws;
    monarch_stage1<<<nblk, NTH, 0, stream>>>(x, L, t1ws);
    monarch_stage2<<<nblk, NTH, 0, stream>>>(t1ws, R, bias, out);
  } else {
    monarch_fused<<<nblk, NTH, 0, stream>>>(x, L, R, bias, out);
  }
}